// Round 13
// baseline (137.644 us; speedup 1.0000x reference)
//
#include <hip/hip_runtime.h>
#include <cmath>

#define B_    64
#define G_    8
#define E_    8
#define OC_   10
#define LL    4096
#define LP    4094
#define COMBINE_SIZE (B_ * G_ * OC_ * LP)   // 20,961,280
#define SLOT  4096                          // floats per ring row

typedef float f32x2 __attribute__((ext_vector_type(2)));

// fast tanh: 1 - 2/(e^{2v}+1); exp overflow/underflow saturates correctly
__device__ __forceinline__ float fast_tanh(float v) {
    const float e = __expf(2.f * v);
    return 1.f - 2.f * __builtin_amdgcn_rcpf(e + 1.f);
}

// granule (16B) swizzle within each 64-granule (1KB) chunk: involution
// c ^= (c>>3). Applied to the GLOBAL source of global_load_lds and to the
// LDS read offsets (both-sides rule); LDS destination stays linear.
__device__ __forceinline__ int gswz(int g) {
    const int c = g & 63;
    return (g & ~63) | (c ^ (c >> 3));
}

// ---- repack conv1 weights: w1[g][o][d][t] -> w1t[g][d][o*3+t] (row pad 32)
__global__ void repack_kernel(const float* __restrict__ w1,
                              float* __restrict__ w1t) {
    const int i = blockIdx.x * 256 + threadIdx.x;   // over 8*32*30
    if (i >= G_ * 32 * 30) return;
    const int g = i / 960, r = i - g * 960;
    const int d = r / 30,  s = r - d * 30;
    const int o = s / 3,   t = s - o * 3;
    w1t[g * 1024 + d * 32 + s] = w1[g * 960 + o * 96 + d * 3 + t];
}

// ---------------- load-balancing loss (1 block, 64 threads) ---------------
__global__ void loss_kernel(const float* __restrict__ gws,
                            float* __restrict__ loss_out) {
    const int tid = threadIdx.x;   // tid = g*8 + e
    float imp = 0.f, ld = 0.f;
    for (int b = 0; b < B_; ++b) {
        const float v = gws[b * 64 + tid];
        imp += v;
        ld  += (v > 0.f) ? 1.f : 0.f;
    }
    float si = imp, sl = ld;
    #pragma unroll
    for (int msk = 1; msk <= 4; msk <<= 1) { si += __shfl_xor(si, msk); sl += __shfl_xor(sl, msk); }
    const float mi = si * 0.125f, ml = sl * 0.125f;
    float di = imp - mi, dl = ld - ml;
    float vi = di * di, vl = dl * dl;
    #pragma unroll
    for (int msk = 1; msk <= 4; msk <<= 1) { vi += __shfl_xor(vi, msk); vl += __shfl_xor(vl, msk); }
    const float cvi = (vi / 7.f) / (mi * mi + 1e-10f);
    const float cvl = (vl / 7.f) / (ml * ml + 1e-10f);
    float c = ((tid & 7) == 0) ? (cvi + cvl) : 0.f;
    #pragma unroll
    for (int msk = 1; msk < 64; msk <<= 1) c += __shfl_xor(c, msk);
    if (tid == 0) *loss_out = 0.01f * c;
}

// ---------------- fused gating + conv1 -> tanh -> gated conv2 --------------
// One block per (b,g): 512 blocks x 512 threads (8 waves), 8 l per thread.
// BARRIER-FREE counted-vmcnt pipeline, LEAD-4 (vmcnt(6), 8 loads in flight,
// 4 ring slots) with WAVE PHASE-STAGGER: wave q processes rows in rotated
// order (d + 4q) & 31 so the CU's waves desynchronize and memory waits of
// some waves overlap compute of others. Packed v_pk_fma_f32 inner loop.
__global__ __launch_bounds__(512, 4) void conv_kernel(
        const float* __restrict__ x,
        const float* __restrict__ w1t,   // repacked [g][d][32]
        const float* __restrict__ b1,
        const float* __restrict__ w2, const float* __restrict__ b2,
        const float* __restrict__ wg,
        float* __restrict__ out,
        float* __restrict__ gws,         // [B*G, E] gates for loss_kernel
        float* __restrict__ gout) {      // [B, E, G] gates output
    const int tid  = threadIdx.x;
    const int lane = tid & 63;
    const int wq   = tid >> 6;           // wave id 0..7
    const int bg   = blockIdx.x;         // b*8 + g
    const int g    = bg & 7;
    const int b    = bg >> 3;

    __shared__ float  ring[4][SLOT];
    __shared__ float2 halo[8][32];       // [wave][row] lane-63 halo pair
    __shared__ float  gin[160];
    __shared__ float  gg[E_];
    __shared__ float  weff[OC_ * OC_];   // [dd][j]
    __shared__ float  beff[OC_];

    const float* xrow = x + (size_t)bg * 32 * LL;   // this block's 32 rows

    // ---- gating input (last-6..last-1 cols of each of the 32 rows) ----
    if (tid < 160) {
        const int d = tid / 5, t = tid - 5 * d;
        gin[tid] = xrow[(size_t)d * LL + (LL - 6 + t)];
    }
    __syncthreads();

    if (tid < 64) {
        const int e = tid & 7, part = tid >> 3;
        const float* wp = wg + g * 1280 + e;
        float logit = 0.f;
        #pragma unroll
        for (int i = 0; i < 20; ++i) {
            const int idx = part * 20 + i;
            logit = fmaf(gin[idx], wp[idx * 8], logit);
        }
        logit += __shfl_xor(logit, 8);
        logit += __shfl_xor(logit, 16);
        logit += __shfl_xor(logit, 32);
        // lanes 0-7 now hold full logits for e=0..7; softmax over them
        float m = logit;
        #pragma unroll
        for (int s = 4; s >= 1; s >>= 1) m = fmaxf(m, __shfl_xor(m, s));
        float p = expf(logit - m);
        float sum = p;
        #pragma unroll
        for (int s = 4; s >= 1; s >>= 1) sum += __shfl_xor(sum, s);
        p /= sum;
        if (tid < 8) {
            float pv[8];
            #pragma unroll
            for (int j = 0; j < 8; ++j) pv[j] = __shfl(p, j);
            int i1 = 0; float v1 = pv[0];
            #pragma unroll
            for (int j = 1; j < 8; ++j) if (pv[j] > v1) { v1 = pv[j]; i1 = j; }
            int i2 = -1; float v2 = -1.f;
            #pragma unroll
            for (int j = 0; j < 8; ++j) if (j != i1 && pv[j] > v2) { v2 = pv[j]; i2 = j; }
            const float denom = v1 + v2 + 1e-6f;
            const float gate = (e == i1) ? v1 / denom
                             : ((e == i2) ? v2 / denom : 0.f);
            gg[e] = gate;
            gws[bg * E_ + e] = gate;
            gout[b * 64 + e * 8 + g] = gate;
        }
    }
    // wave-private lane-63 halo table: halo[wq][row] = x[row][wq*512+512,+513]
    // (wq==7 loads a safe dummy; its halo feeds only discarded outputs)
    if (lane < 32) {
        const float* hp = xrow + (size_t)lane * LL + (wq < 7 ? wq * 512 + 512 : 0);
        halo[wq][lane] = *reinterpret_cast<const float2*>(hp);
    }
    __syncthreads();

    // gated conv2 weights from gg
    if (tid < 100) {
        const int dd = tid / 10, j = tid - dd * 10;
        float s = 0.f;
        #pragma unroll
        for (int e = 0; e < 8; ++e)
            s = fmaf(gg[e], w2[(g * 80 + dd * 8 + e) * 10 + j], s);
        weff[tid] = s;
    } else if (tid < 110) {
        const int dd = tid - 100;
        float s = 0.f;
        #pragma unroll
        for (int e = 0; e < 8; ++e)
            s = fmaf(gg[e], b2[g * 80 + dd * 8 + e], s);
        beff[dd] = s;
    }
    // weff/beff published by the __syncthreads after the main loop.

    const float* wgt = w1t + g * 1024;          // wave-uniform base
    const float* b1g = b1 + g * OC_;            // wave-uniform

    // per-lane swizzled source offset within this wave's 1KB chunks (floats)
    const int sl = (lane ^ (lane >> 3)) * 4;

#define STAGE(r)                                                              \
    {                                                                         \
        const float* gb = xrow + (size_t)(r) * LL + wq * 512;                 \
        float* lb = &ring[(r) & 3][wq * 512];                                 \
        __builtin_amdgcn_global_load_lds(                                     \
            (const __attribute__((address_space(1))) void*)(gb + sl),         \
            (__attribute__((address_space(3))) void*)lb, 16, 0, 0);           \
        __builtin_amdgcn_global_load_lds(                                     \
            (const __attribute__((address_space(1))) void*)(gb + 256 + sl),   \
            (__attribute__((address_space(3))) void*)(lb + 256), 16, 0, 0);   \
    }

#define WAITV(n) asm volatile("s_waitcnt vmcnt(" #n ")" ::: "memory");

    // packed accumulators: acc2[o][q] covers k = 2q, 2q+1
    f32x2 acc2[10][4];
    #pragma unroll
    for (int o = 0; o < 10; ++o) {
        const float bv = b1g[o];
        #pragma unroll
        for (int q = 0; q < 4; ++q) acc2[o][q] = (f32x2){bv, bv};
    }

    // fixed swizzled read offsets (floats) for this thread's 10-float window;
    // p3 (2 halo floats) comes from the same wave's staged span for lanes
    // 0-62; lane 63 overrides from the halo table (tid 511 clamped in-bounds).
    const int p1 = gswz(tid * 2) * 4;
    const int p2 = gswz(tid * 2 + 1) * 4;
    const int p3 = (tid == 511) ? 0 : gswz(tid * 2 + 2) * 4;
    const bool l63 = (lane == 63);

#define COMPROW(dd)                                                           \
    {                                                                         \
        const float* sb = ring[(dd) & 3];                                     \
        float xw[10];                                                         \
        *reinterpret_cast<float4*>(&xw[0]) =                                  \
            *reinterpret_cast<const float4*>(sb + p1);                        \
        *reinterpret_cast<float4*>(&xw[4]) =                                  \
            *reinterpret_cast<const float4*>(sb + p2);                        \
        const float2 nb = *reinterpret_cast<const float2*>(sb + p3);          \
        const float2 hv = halo[wq][(dd)];                                     \
        xw[8] = l63 ? hv.x : nb.x;                                            \
        xw[9] = l63 ? hv.y : nb.y;                                            \
        f32x2 xv[5], xb[4];                                                   \
        _Pragma("unroll")                                                     \
        for (int q = 0; q < 5; ++q) xv[q] = (f32x2){xw[2*q], xw[2*q+1]};      \
        _Pragma("unroll")                                                     \
        for (int q = 0; q < 4; ++q) xb[q] = (f32x2){xw[2*q+1], xw[2*q+2]};    \
        const float* wr = wgt + (dd) * 32;                                    \
        _Pragma("unroll")                                                     \
        for (int o = 0; o < 10; ++o) {                                        \
            const float w0 = wr[o * 3];                                       \
            const float wA = wr[o * 3 + 1];                                   \
            const float wB = wr[o * 3 + 2];                                   \
            const f32x2 W0 = {w0, w0}, WA = {wA, wA}, WB = {wB, wB};          \
            _Pragma("unroll")                                                 \
            for (int q = 0; q < 4; ++q)                                       \
                acc2[o][q] = __builtin_elementwise_fma(xv[q + 1], WB,         \
                             __builtin_elementwise_fma(xb[q],     WA,         \
                             __builtin_elementwise_fma(xv[q],     W0,         \
                                                       acc2[o][q])));         \
        }                                                                     \
    }

    // wave phase-stagger: wave q walks rows (d + 4q) & 31; slot = row & 3
    // is unaffected (4q ≡ 0 mod 4), so ring reuse logic is unchanged.
#define ROW(d) (((d) + wq * 4) & 31)

    // prologue: stage rows 0..3 of this wave's schedule (8 loads in flight)
    STAGE(ROW(0)) STAGE(ROW(1)) STAGE(ROW(2)) STAGE(ROW(3))

    #pragma unroll 1
    for (int d = 0; d < 28; ++d) {
        WAITV(6)                  // this wave's row-d loads complete
        COMPROW(ROW(d))
        STAGE(ROW(d + 4))         // slot (d+4)&3 freed by COMPROW(ROW(d))
    }
    WAITV(6) COMPROW(ROW(28))
    WAITV(4) COMPROW(ROW(29))
    WAITV(2) COMPROW(ROW(30))
    WAITV(0) COMPROW(ROW(31))

#undef ROW
#undef STAGE
#undef WAITV
#undef COMPROW

    #pragma unroll
    for (int o = 0; o < 10; ++o)
        #pragma unroll
        for (int q = 0; q < 4; ++q) {
            acc2[o][q][0] = fast_tanh(acc2[o][q][0]);
            acc2[o][q][1] = fast_tanh(acc2[o][q][1]);
        }

    __syncthreads();   // publish weff/beff (written in prologue)

    const int l = tid * 8;
    float* ob = out + (size_t)bg * OC_ * LP + l;
    const bool full = (l + 8 <= LP);
    #pragma unroll
    for (int dd = 0; dd < 10; ++dd) {
        const float* wr = weff + dd * 10;
        const float bv = beff[dd];
        f32x2 r2[4];
        #pragma unroll
        for (int q = 0; q < 4; ++q) r2[q] = (f32x2){bv, bv};
        #pragma unroll
        for (int j = 0; j < 10; ++j) {
            const float w = wr[j];
            const f32x2 W = {w, w};
            #pragma unroll
            for (int q = 0; q < 4; ++q)
                r2[q] = __builtin_elementwise_fma(acc2[j][q], W, r2[q]);
        }
        float* op = ob + (size_t)dd * LP;
        if (full) {
            #pragma unroll
            for (int q = 0; q < 4; ++q)
                *reinterpret_cast<float2*>(op + 2 * q) =
                    make_float2(r2[q][0], r2[q][1]);
        } else {
            #pragma unroll
            for (int q = 0; q < 4; ++q) {
                if (l + 2 * q     < LP) op[2 * q]     = r2[q][0];
                if (l + 2 * q + 1 < LP) op[2 * q + 1] = r2[q][1];
            }
        }
    }
}

extern "C" void kernel_launch(void* const* d_in, const int* in_sizes, int n_in,
                              void* d_out, int out_size, void* d_ws, size_t ws_size,
                              hipStream_t stream) {
    (void)in_sizes; (void)n_in; (void)out_size; (void)ws_size;
    const float* x  = (const float*)d_in[0];
    const float* w1 = (const float*)d_in[1];
    const float* b1 = (const float*)d_in[2];
    const float* w2 = (const float*)d_in[3];
    const float* b2 = (const float*)d_in[4];
    const float* wg = (const float*)d_in[5];
    float* out      = (float*)d_out;
    float* gws      = (float*)d_ws;                         // [B,G,E]
    float* w1t      = (float*)d_ws + B_ * G_ * E_;          // [g][d][32]
    float* loss_out = out + COMBINE_SIZE;
    float* gout     = out + COMBINE_SIZE + 1;

    repack_kernel<<<(G_ * 32 * 30 + 255) / 256, 256, 0, stream>>>(w1, w1t);
    conv_kernel<<<B_ * G_, 512, 0, stream>>>(x, w1t, b1, w2, b2, wg,
                                             out, gws, gout);
    loss_kernel<<<1, 64, 0, stream>>>(gws, loss_out);
}

// Round 14
// 98.980 us; speedup vs baseline: 1.3906x; 1.3906x over previous
//
#include <hip/hip_runtime.h>
#include <cmath>

#define B_    64
#define G_    8
#define E_    8
#define OC_   10
#define LL    4096
#define LP    4094
#define COMBINE_SIZE (B_ * G_ * OC_ * LP)   // 20,961,280
#define SLOT  4096                          // floats per ring row

typedef float f32x2 __attribute__((ext_vector_type(2)));
#define AS1 __attribute__((address_space(1)))
#define AS3 __attribute__((address_space(3)))

// fast tanh: 1 - 2/(e^{2v}+1); exp overflow/underflow saturates correctly
__device__ __forceinline__ float fast_tanh(float v) {
    const float e = __expf(2.f * v);
    return 1.f - 2.f * __builtin_amdgcn_rcpf(e + 1.f);
}

// granule (16B) swizzle within each 64-granule (1KB) chunk: involution
// c ^= (c>>3). Applied to the GLOBAL source of global_load_lds and to the
// LDS read offsets (both-sides rule); LDS destination stays linear.
__device__ __forceinline__ int gswz(int g) {
    const int c = g & 63;
    return (g & ~63) | (c ^ (c >> 3));
}

// ---- repack conv1 weights: w1[g][o][d][t] -> w1t[g][d][o*3+t] (row pad 32)
__global__ void repack_kernel(const float* __restrict__ w1,
                              float* __restrict__ w1t) {
    const int i = blockIdx.x * 256 + threadIdx.x;   // over 8*32*30
    if (i >= G_ * 32 * 30) return;
    const int g = i / 960, r = i - g * 960;
    const int d = r / 30,  s = r - d * 30;
    const int o = s / 3,   t = s - o * 3;
    w1t[g * 1024 + d * 32 + s] = w1[g * 960 + o * 96 + d * 3 + t];
}

// ---------------- load-balancing loss (1 block, 64 threads) ---------------
__global__ void loss_kernel(const float* __restrict__ gws,
                            float* __restrict__ loss_out) {
    const int tid = threadIdx.x;   // tid = g*8 + e
    float imp = 0.f, ld = 0.f;
    for (int b = 0; b < B_; ++b) {
        const float v = gws[b * 64 + tid];
        imp += v;
        ld  += (v > 0.f) ? 1.f : 0.f;
    }
    float si = imp, sl = ld;
    #pragma unroll
    for (int msk = 1; msk <= 4; msk <<= 1) { si += __shfl_xor(si, msk); sl += __shfl_xor(sl, msk); }
    const float mi = si * 0.125f, ml = sl * 0.125f;
    float di = imp - mi, dl = ld - ml;
    float vi = di * di, vl = dl * dl;
    #pragma unroll
    for (int msk = 1; msk <= 4; msk <<= 1) { vi += __shfl_xor(vi, msk); vl += __shfl_xor(vl, msk); }
    const float cvi = (vi / 7.f) / (mi * mi + 1e-10f);
    const float cvl = (vl / 7.f) / (ml * ml + 1e-10f);
    float c = ((tid & 7) == 0) ? (cvi + cvl) : 0.f;
    #pragma unroll
    for (int msk = 1; msk < 64; msk <<= 1) c += __shfl_xor(c, msk);
    if (tid == 0) *loss_out = 0.01f * c;
}

// ---------------- fused gating + conv1 -> tanh -> gated conv2 --------------
// One block per (b,g): 512 blocks x 512 threads (8 waves), 8 l per thread.
// DRAIN-FREE prologue: gating gather and halo fill use global_load_lds (no
// compiler vmcnt waits), stages issue immediately after, WAITV(6) + raw
// s_barrier (no vmcnt drain) -- 6 staged loads stay in flight across the
// gate computation. weff/beff deferred to post-loop (vmcnt naturally 0).
// Main loop: barrier-free counted-vmcnt (lead-3, vmcnt(4)), packed fp32.
__global__ __launch_bounds__(512, 4) void conv_kernel(
        const float* __restrict__ x,
        const float* __restrict__ w1t,   // repacked [g][d][32]
        const float* __restrict__ b1,
        const float* __restrict__ w2, const float* __restrict__ b2,
        const float* __restrict__ wg,
        float* __restrict__ out,
        float* __restrict__ gws,         // [B*G, E] gates for loss_kernel
        float* __restrict__ gout) {      // [B, E, G] gates output
    const int tid  = threadIdx.x;
    const int lane = tid & 63;
    const int wq   = tid >> 6;           // wave id 0..7
    const int bg   = blockIdx.x;         // b*8 + g
    const int g    = bg & 7;
    const int b    = bg >> 3;

    __shared__ float  ring[4][SLOT];
    __shared__ float2 halo[8][32];       // [wave][row] lane-63 halo pair
    __shared__ float  gin[192];          // 160 used (pad to 3 waves)
    __shared__ float  gg[E_];
    __shared__ float  weff[OC_ * OC_];   // [dd][j]
    __shared__ float  beff[OC_];

    const float* xrow = x + (size_t)bg * 32 * LL;   // this block's 32 rows
    // per-lane swizzled source offset within this wave's 1KB chunks (floats)
    const int sl = (lane ^ (lane >> 3)) * 4;

#define STAGE(r)                                                              \
    {                                                                         \
        const float* gb = xrow + (size_t)(r) * LL + wq * 512;                 \
        float* lb = &ring[(r) & 3][wq * 512];                                 \
        __builtin_amdgcn_global_load_lds(                                     \
            (const AS1 void*)(gb + sl),                                       \
            (AS3 void*)lb, 16, 0, 0);                                         \
        __builtin_amdgcn_global_load_lds(                                     \
            (const AS1 void*)(gb + 256 + sl),                                 \
            (AS3 void*)(lb + 256), 16, 0, 0);                                 \
    }

#define WAITV(n) asm volatile("s_waitcnt vmcnt(" #n ")" ::: "memory");

    // ---- 1. gating-input gather via glds (waves 0-2; 4B per lane) ----
    if (tid < 160) {
        const int dd = tid / 5, t = tid - 5 * dd;
        __builtin_amdgcn_global_load_lds(
            (const AS1 void*)(xrow + (size_t)dd * LL + (LL - 6 + t)),
            (AS3 void*)(gin + (wq << 6)), 4, 0, 0);
    }
    // ---- 2. halo table via glds: halo[wq][r] = x[r][wq*512+512 .. +513] ----
    {
        const int hr = lane >> 1, hc = lane & 1;
        const float* hsrc = xrow + (size_t)hr * LL
                          + (wq < 7 ? wq * 512 + 512 + hc : hc);  // wq7 dummy
        __builtin_amdgcn_global_load_lds(
            (const AS1 void*)hsrc,
            (AS3 void*)(reinterpret_cast<float*>(halo) + (wq << 6)), 4, 0, 0);
    }
    // ---- 3. stages start immediately (memory moving during gating) ----
    STAGE(0) STAGE(1) STAGE(2)

    // ---- 4. gather+halo landed (oldest 2 of <=8); stages stay in flight ----
    WAITV(6)
    __builtin_amdgcn_s_barrier();

    // ---- 5. gate softmax + top2 (wave 0 lanes) ----
    if (tid < 64) {
        const int e = tid & 7, part = tid >> 3;
        const float* wp = wg + g * 1280 + e;
        float logit = 0.f;
        #pragma unroll
        for (int i = 0; i < 20; ++i) {
            const int idx = part * 20 + i;
            logit = fmaf(gin[idx], wp[idx * 8], logit);
        }
        logit += __shfl_xor(logit, 8);
        logit += __shfl_xor(logit, 16);
        logit += __shfl_xor(logit, 32);
        float m = logit;
        #pragma unroll
        for (int s = 4; s >= 1; s >>= 1) m = fmaxf(m, __shfl_xor(m, s));
        float p = expf(logit - m);
        float sum = p;
        #pragma unroll
        for (int s = 4; s >= 1; s >>= 1) sum += __shfl_xor(sum, s);
        p /= sum;
        if (tid < 8) {
            float pv[8];
            #pragma unroll
            for (int j = 0; j < 8; ++j) pv[j] = __shfl(p, j);
            int i1 = 0; float v1 = pv[0];
            #pragma unroll
            for (int j = 1; j < 8; ++j) if (pv[j] > v1) { v1 = pv[j]; i1 = j; }
            int i2 = -1; float v2 = -1.f;
            #pragma unroll
            for (int j = 0; j < 8; ++j) if (j != i1 && pv[j] > v2) { v2 = pv[j]; i2 = j; }
            const float denom = v1 + v2 + 1e-6f;
            const float gate = (e == i1) ? v1 / denom
                             : ((e == i2) ? v2 / denom : 0.f);
            gg[e] = gate;
            gws[bg * E_ + e] = gate;                 // stores: vmcnt-safe
            gout[b * 64 + e * 8 + g] = gate;
        }
    }
    // ---- 6. publish gg (LDS-only wait; NO vmcnt drain) ----
    asm volatile("s_waitcnt lgkmcnt(0)" ::: "memory");
    __builtin_amdgcn_s_barrier();

    const float* b1g = b1 + g * OC_;            // wave-uniform
    const float* wgt = w1t + g * 1024;          // wave-uniform base

    // packed accumulators: acc2[o][q] covers k = 2q, 2q+1
    f32x2 acc2[10][4];
    #pragma unroll
    for (int o = 0; o < 10; ++o) {
        const float bv = b1g[o];
        #pragma unroll
        for (int q = 0; q < 4; ++q) acc2[o][q] = (f32x2){bv, bv};
    }

    // fixed swizzled read offsets (floats) for this thread's 8-float window
    const int p1 = gswz(tid * 2) * 4;
    const int p2 = gswz(tid * 2 + 1) * 4;
    const bool l63 = (lane == 63);

#define COMPROW(dd)                                                           \
    {                                                                         \
        const float* sb = ring[(dd) & 3];                                     \
        float xw[10];                                                         \
        *reinterpret_cast<float4*>(&xw[0]) =                                  \
            *reinterpret_cast<const float4*>(sb + p1);                        \
        *reinterpret_cast<float4*>(&xw[4]) =                                  \
            *reinterpret_cast<const float4*>(sb + p2);                        \
        const float2 hv = halo[wq][(dd)];                                     \
        const float n0 = __shfl_down(xw[0], 1);                               \
        const float n1 = __shfl_down(xw[1], 1);                               \
        xw[8] = l63 ? hv.x : n0;                                              \
        xw[9] = l63 ? hv.y : n1;                                              \
        f32x2 xv[5], xb[4];                                                   \
        _Pragma("unroll")                                                     \
        for (int q = 0; q < 5; ++q) xv[q] = (f32x2){xw[2*q], xw[2*q+1]};      \
        _Pragma("unroll")                                                     \
        for (int q = 0; q < 4; ++q) xb[q] = (f32x2){xw[2*q+1], xw[2*q+2]};    \
        const float* wr = wgt + (dd) * 32;                                    \
        _Pragma("unroll")                                                     \
        for (int o = 0; o < 10; ++o) {                                        \
            const float w0 = wr[o * 3];                                       \
            const float wA = wr[o * 3 + 1];                                   \
            const float wB = wr[o * 3 + 2];                                   \
            const f32x2 W0 = {w0, w0}, WA = {wA, wA}, WB = {wB, wB};          \
            _Pragma("unroll")                                                 \
            for (int q = 0; q < 4; ++q)                                       \
                acc2[o][q] = __builtin_elementwise_fma(xv[q + 1], WB,         \
                             __builtin_elementwise_fma(xb[q],     WA,         \
                             __builtin_elementwise_fma(xv[q],     W0,         \
                                                       acc2[o][q])));         \
        }                                                                     \
    }

    #pragma unroll 1
    for (int d = 0; d < 29; ++d) {
        WAITV(4)              // this wave's row-d loads complete
        COMPROW(d)
        STAGE(d + 3)          // refill; slot (d+3)&3 was consumed at d-1
    }
    WAITV(4) COMPROW(29)
    WAITV(2) COMPROW(30)
    WAITV(0) COMPROW(31)

#undef STAGE
#undef WAITV
#undef COMPROW

    #pragma unroll
    for (int o = 0; o < 10; ++o)
        #pragma unroll
        for (int q = 0; q < 4; ++q) {
            acc2[o][q][0] = fast_tanh(acc2[o][q][0]);
            acc2[o][q][1] = fast_tanh(acc2[o][q][1]);
        }

    // ---- gated conv2 weights (post-loop: vmcnt is naturally 0 here; gg
    // visibility guaranteed by prologue barrier #2) ----
    if (tid < 100) {
        const int dd = tid / 10, j = tid - dd * 10;
        float s = 0.f;
        #pragma unroll
        for (int e = 0; e < 8; ++e)
            s = fmaf(gg[e], w2[(g * 80 + dd * 8 + e) * 10 + j], s);
        weff[tid] = s;
    } else if (tid < 110) {
        const int dd = tid - 100;
        float s = 0.f;
        #pragma unroll
        for (int e = 0; e < 8; ++e)
            s = fmaf(gg[e], b2[g * 80 + dd * 8 + e], s);
        beff[dd] = s;
    }
    __syncthreads();   // publish weff/beff (cheap: counters already drained)

    const int l = tid * 8;
    float* ob = out + (size_t)bg * OC_ * LP + l;
    const bool full = (l + 8 <= LP);
    #pragma unroll
    for (int dd = 0; dd < 10; ++dd) {
        const float* wr = weff + dd * 10;
        const float bv = beff[dd];
        f32x2 r2[4];
        #pragma unroll
        for (int q = 0; q < 4; ++q) r2[q] = (f32x2){bv, bv};
        #pragma unroll
        for (int j = 0; j < 10; ++j) {
            const float w = wr[j];
            const f32x2 W = {w, w};
            #pragma unroll
            for (int q = 0; q < 4; ++q)
                r2[q] = __builtin_elementwise_fma(acc2[j][q], W, r2[q]);
        }
        float* op = ob + (size_t)dd * LP;
        if (full) {
            #pragma unroll
            for (int q = 0; q < 4; ++q)
                *reinterpret_cast<float2*>(op + 2 * q) =
                    make_float2(r2[q][0], r2[q][1]);
        } else {
            #pragma unroll
            for (int q = 0; q < 4; ++q) {
                if (l + 2 * q     < LP) op[2 * q]     = r2[q][0];
                if (l + 2 * q + 1 < LP) op[2 * q + 1] = r2[q][1];
            }
        }
    }
}

extern "C" void kernel_launch(void* const* d_in, const int* in_sizes, int n_in,
                              void* d_out, int out_size, void* d_ws, size_t ws_size,
                              hipStream_t stream) {
    (void)in_sizes; (void)n_in; (void)out_size; (void)ws_size;
    const float* x  = (const float*)d_in[0];
    const float* w1 = (const float*)d_in[1];
    const float* b1 = (const float*)d_in[2];
    const float* w2 = (const float*)d_in[3];
    const float* b2 = (const float*)d_in[4];
    const float* wg = (const float*)d_in[5];
    float* out      = (float*)d_out;
    float* gws      = (float*)d_ws;                         // [B,G,E]
    float* w1t      = (float*)d_ws + B_ * G_ * E_;          // [g][d][32]
    float* loss_out = out + COMBINE_SIZE;
    float* gout     = out + COMBINE_SIZE + 1;

    repack_kernel<<<(G_ * 32 * 30 + 255) / 256, 256, 0, stream>>>(w1, w1t);
    conv_kernel<<<B_ * G_, 512, 0, stream>>>(x, w1t, b1, w2, b2, wg,
                                             out, gws, gout);
    loss_kernel<<<1, 64, 0, stream>>>(gws, loss_out);
}